// Round 1
// baseline (56.196 us; speedup 1.0000x reference)
//
#include <hip/hip_runtime.h>
#include <math.h>

// Problem constants (from reference): logits (64,2048) f32, gn (32,64,2048) f32,
// out (32,64,16,2048) f32 = one_hot of ascending-sorted top-16 indices of logits+gn.
#define K_SEL   16
#define VOCAB   2048
#define NROWS   2048   // BS(32) * D0(64)
#define THREADS 256

__global__ __launch_bounds__(THREADS) void topk_onehot_kernel(
    const float* __restrict__ logits,   // (64, 2048)
    const float* __restrict__ gn,       // (32, 64, 2048)
    float* __restrict__ out)            // (32, 64, 16, 2048)
{
    const int row  = blockIdx.x;        // row = bs*64 + d0
    const int d0   = row & 63;
    const int tid  = threadIdx.x;
    const int lane = tid & 63;
    const int wid  = tid >> 6;

    // Each thread owns 8 columns: [c0, c0+4) and [c1, c1+4)
    const int c0 = tid * 4;
    const int c1 = 1024 + tid * 4;

    const float4 g0 = *reinterpret_cast<const float4*>(gn + (size_t)row * VOCAB + c0);
    const float4 g1 = *reinterpret_cast<const float4*>(gn + (size_t)row * VOCAB + c1);
    const float4 l0 = *reinterpret_cast<const float4*>(logits + (size_t)d0 * VOCAB + c0);
    const float4 l1 = *reinterpret_cast<const float4*>(logits + (size_t)d0 * VOCAB + c1);

    float v[8];
    v[0] = l0.x + g0.x; v[1] = l0.y + g0.y; v[2] = l0.z + g0.z; v[3] = l0.w + g0.w;
    v[4] = l1.x + g1.x; v[5] = l1.y + g1.y; v[6] = l1.z + g1.z; v[7] = l1.w + g1.w;

    __shared__ float swv[4];
    __shared__ int   swi[4];
    __shared__ int   sel[K_SEL];
    __shared__ int   sorted[K_SEL];

    // 16 rounds of block-wide argmax (value desc, index asc tie-break = lax.top_k)
    for (int k = 0; k < K_SEL; ++k) {
        float bestv = v[0];
        int   besti = c0;
        #pragma unroll
        for (int j = 1; j < 8; ++j) {
            const int cj = (j < 4) ? (c0 + j) : (c1 + (j - 4));
            // ascending column scan + strict '>' keeps the lowest index on ties
            if (v[j] > bestv) { bestv = v[j]; besti = cj; }
        }
        // 64-lane butterfly reduce
        #pragma unroll
        for (int off = 1; off < 64; off <<= 1) {
            const float ov = __shfl_xor(bestv, off);
            const int   oi = __shfl_xor(besti, off);
            if (ov > bestv || (ov == bestv && oi < besti)) { bestv = ov; besti = oi; }
        }
        if (lane == 0) { swv[wid] = bestv; swi[wid] = besti; }
        __syncthreads();
        if (tid == 0) {
            float bv = swv[0]; int bi = swi[0];
            #pragma unroll
            for (int w = 1; w < 4; ++w) {
                if (swv[w] > bv || (swv[w] == bv && swi[w] < bi)) { bv = swv[w]; bi = swi[w]; }
            }
            sel[k] = bi;
        }
        __syncthreads();
        const int widx = sel[k];
        // knock out the winner in its owner's registers
        #pragma unroll
        for (int j = 0; j < 8; ++j) {
            const int cj = (j < 4) ? (c0 + j) : (c1 + (j - 4));
            if (cj == widx) v[j] = -INFINITY;
        }
    }

    // rank-sort the 16 (distinct) indices ascending
    if (tid < K_SEL) {
        const int my = sel[tid];
        int rank = 0;
        #pragma unroll
        for (int j = 0; j < K_SEL; ++j) rank += (sel[j] < my) ? 1 : 0;
        sorted[rank] = my;
    }
    __syncthreads();

    // write 16 one-hot rows, fully coalesced float4 stores
    float* orow = out + (size_t)row * K_SEL * VOCAB;
    #pragma unroll
    for (int k = 0; k < K_SEL; ++k) {
        const int one = sorted[k];
        float4 a, b;
        a.x = (one == c0 + 0) ? 1.0f : 0.0f;
        a.y = (one == c0 + 1) ? 1.0f : 0.0f;
        a.z = (one == c0 + 2) ? 1.0f : 0.0f;
        a.w = (one == c0 + 3) ? 1.0f : 0.0f;
        b.x = (one == c1 + 0) ? 1.0f : 0.0f;
        b.y = (one == c1 + 1) ? 1.0f : 0.0f;
        b.z = (one == c1 + 2) ? 1.0f : 0.0f;
        b.w = (one == c1 + 3) ? 1.0f : 0.0f;
        *reinterpret_cast<float4*>(orow + (size_t)k * VOCAB + c0) = a;
        *reinterpret_cast<float4*>(orow + (size_t)k * VOCAB + c1) = b;
    }
}

extern "C" void kernel_launch(void* const* d_in, const int* in_sizes, int n_in,
                              void* d_out, int out_size, void* d_ws, size_t ws_size,
                              hipStream_t stream) {
    const float* logits = (const float*)d_in[0];   // 64*2048
    const float* gn     = (const float*)d_in[1];   // 32*64*2048
    float* out          = (float*)d_out;           // 32*64*16*2048

    hipLaunchKernelGGL(topk_onehot_kernel, dim3(NROWS), dim3(THREADS), 0, stream,
                       logits, gn, out);
}

// Round 2
// 51.932 us; speedup vs baseline: 1.0821x; 1.0821x over previous
//
#include <hip/hip_runtime.h>
#include <math.h>

// out (32,64,16,2048) f32 = one_hot(ascending-sorted top-16 indices of logits+gn).
// Forward value of stop_gradient(hard-soft)+soft == hard exactly (0) / ~1ulp (1).
#define K_SEL   16
#define VOCAB   2048
#define NROWS   2048   // BS(32) * D0(64)

// One wave per row. No LDS, no __syncthreads -> no forced vmcnt drains.
// Zero-stores interleaved with the 16 selection rounds so the memory pipe is
// saturated from the start; 1.0 overwrites after an explicit vmcnt(0) drain.
__global__ __launch_bounds__(64) void topk_onehot_kernel(
    const float* __restrict__ logits,   // (64, 2048)
    const float* __restrict__ gn,       // (32, 64, 2048)
    float* __restrict__ out)            // (32, 64, 16, 2048)
{
    const int row  = blockIdx.x;        // row = bs*64 + d0
    const int d0   = row & 63;
    const int lane = threadIdx.x;       // 0..63 (one wave)

    const float* grow = gn     + (size_t)row * VOCAB;
    const float* lrow = logits + (size_t)d0  * VOCAB;
    float*       orow = out    + (size_t)row * (K_SEL * VOCAB);

    // lane owns columns c = seg*256 + lane*4 + j, seg=0..7, j=0..3 (ascending in (seg,j))
    float v[32];
    #pragma unroll
    for (int seg = 0; seg < 8; ++seg) {
        const int c = seg * 256 + lane * 4;
        const float4 g = *reinterpret_cast<const float4*>(grow + c);
        const float4 l = *reinterpret_cast<const float4*>(lrow + c);
        v[seg * 4 + 0] = l.x + g.x;
        v[seg * 4 + 1] = l.y + g.y;
        v[seg * 4 + 2] = l.z + g.z;
        v[seg * 4 + 3] = l.w + g.w;
    }

    // local argmax; ascending scan + strict '>' keeps lowest index on ties
    float lv = v[0]; int ls = 0;
    #pragma unroll
    for (int i = 1; i < 32; ++i) { if (v[i] > lv) { lv = v[i]; ls = i; } }

    const float4 z4 = make_float4(0.f, 0.f, 0.f, 0.f);
    int sel[K_SEL];

    #pragma unroll
    for (int k = 0; k < K_SEL; ++k) {
        // zero-store one output row per round (8 x float4, 1KB/instr coalesced)
        #pragma unroll
        for (int seg = 0; seg < 8; ++seg) {
            *reinterpret_cast<float4*>(orow + (size_t)k * VOCAB + seg * 256 + lane * 4) = z4;
        }
        // wave argmax via 64-lane butterfly on (value desc, col asc)
        float bv = lv;
        int   bc = ((ls >> 2) << 8) + lane * 4 + (ls & 3);
        #pragma unroll
        for (int off = 1; off < 64; off <<= 1) {
            const float ov = __shfl_xor(bv, off);
            const int   oc = __shfl_xor(bc, off);
            if (ov > bv || (ov == bv && oc < bc)) { bv = ov; bc = oc; }
        }
        sel[k] = bc;  // wave-uniform after butterfly
        // owner lane knocks out the winner and rescans its local max
        if (lane == ((bc >> 2) & 63)) {
            const int s = (((bc >> 8) & 7) << 2) | (bc & 3);
            lv = -INFINITY; ls = 0;
            #pragma unroll
            for (int i = 0; i < 32; ++i) {
                if (i == s) v[i] = -INFINITY;
                if (v[i] > lv) { lv = v[i]; ls = i; }
            }
        }
    }

    // drain zero stores (HW order + compiler reorder fence) before overwrites
    asm volatile("s_waitcnt vmcnt(0)" ::: "memory");

    // one-hot row for sel[k] is its ascending rank among the 16 (all distinct)
    #pragma unroll
    for (int k = 0; k < K_SEL; ++k) {
        int r = 0;
        #pragma unroll
        for (int j = 0; j < K_SEL; ++j) r += (sel[j] < sel[k]) ? 1 : 0;
        if (lane == ((sel[k] >> 2) & 63)) {
            orow[(size_t)r * VOCAB + sel[k]] = 1.0f;
        }
    }
}

extern "C" void kernel_launch(void* const* d_in, const int* in_sizes, int n_in,
                              void* d_out, int out_size, void* d_ws, size_t ws_size,
                              hipStream_t stream) {
    const float* logits = (const float*)d_in[0];   // 64*2048
    const float* gn     = (const float*)d_in[1];   // 32*64*2048
    float* out          = (float*)d_out;           // 32*64*16*2048

    hipLaunchKernelGGL(topk_onehot_kernel, dim3(NROWS), dim3(64), 0, stream,
                       logits, gn, out);
}